// Round 10
// baseline (199.645 us; speedup 1.0000x reference)
//
#include <hip/hip_runtime.h>
#include <math.h>

#define HW      1792
#define NMEM    28672
#define NCHUNK  3584          // NMEM/8 chunks of 8
#define TOPK    30
#define CTARGET 64
#define BINS    2048
#define L1SHIFT 20            // level-1 bin = key >> 20 (11 bits)
#define L2SHIFT 9             // level-2 sub = (key >> 9) & 2047 (next 11 bits)
#define VCACHE  1024
#define BCAP    512
#define SIMB    448           // 14 p-blocks(128px) x 32 strips
#define WPS     7             // 128-n windows per strip

typedef __attribute__((ext_vector_type(8))) short bf16x8;
typedef __attribute__((ext_vector_type(8))) unsigned short u16x8;
typedef __attribute__((ext_vector_type(4))) float f32x4;
typedef __attribute__((ext_vector_type(4))) _Float16 h4;

static __device__ __forceinline__ unsigned short f2bf(float v) {
  unsigned b = __float_as_uint(v);
  return (unsigned short)((b + 0x7FFFu + ((b >> 16) & 1u)) >> 16);
}
static __device__ __forceinline__ float bf2f(unsigned short h) {
  return __uint_as_float(((unsigned)h) << 16);
}
static __device__ __forceinline__ unsigned fkey(float v) {
  return __float_as_uint(-v) & 0x7FFFFFFFu;
}
static __device__ __forceinline__ void gl_lds16(const void* g, void* l) {
  __builtin_amdgcn_global_load_lds(
      (const __attribute__((address_space(1))) unsigned*)g,
      (__attribute__((address_space(3))) unsigned*)l, 16, 0, 0);
}

// ---------------------------------------------------------------------------
// Prep B: Bh[s][n][8] bf16-hi (s=0..7: mk, s=8..15: mk^2); mkT[n][64] fp32;
// shr_s = mem_shr/8.
// ---------------------------------------------------------------------------
__global__ __launch_bounds__(256)
void k_prep_b(const float* __restrict__ mk, const float* __restrict__ shr_in,
              unsigned short* __restrict__ Bh,
              float* __restrict__ mkT, float* __restrict__ shr_s)
{
  const int n = blockIdx.x * 256 + threadIdx.x;
  shr_s[n] = shr_in[n] * 0.125f;
  for (int cb = 0; cb < 64; cb += 8) {
    u16x8 h1, h2;
    float vv[8];
    #pragma unroll
    for (int j = 0; j < 8; ++j) {
      float v = mk[(size_t)(cb + j) * NMEM + n];
      vv[j] = v;
      h1[j] = f2bf(v);
      h2[j] = f2bf(v * v);
    }
    const int s = cb >> 3;
    *reinterpret_cast<u16x8*>(&Bh[((size_t)s * NMEM + n) * 8])       = h1;
    *reinterpret_cast<u16x8*>(&Bh[((size_t)(s + 8) * NMEM + n) * 8]) = h2;
    *reinterpret_cast<float4*>(&mkT[(size_t)n * 64 + cb])     = make_float4(vv[0], vv[1], vv[2], vv[3]);
    *reinterpret_cast<float4*>(&mkT[(size_t)n * 64 + cb + 4]) = make_float4(vv[4], vv[5], vv[6], vv[7]);
  }
}

// ---------------------------------------------------------------------------
// Prep U: Uh/Ul[s][p][8] bf16 hi/lo. s=0..7: 2*qk*qs, s=8..15: -qs. bsq[p].
// ---------------------------------------------------------------------------
__global__ __launch_bounds__(256)
void k_prep_u(const float* __restrict__ q_key, const float* __restrict__ q_sel,
              unsigned short* __restrict__ Uh, unsigned short* __restrict__ Ul,
              float* __restrict__ bsq)
{
  const int p = blockIdx.x * 256 + threadIdx.x;
  float bs = 0.f;
  for (int cb = 0; cb < 64; cb += 8) {
    u16x8 h1, l1, h2, l2;
    #pragma unroll
    for (int j = 0; j < 8; ++j) {
      int c = cb + j;
      float k = q_key[(size_t)c * HW + p];
      float s = q_sel[(size_t)c * HW + p];
      float u = 2.f * k * s;
      float w = -s;
      bs = fmaf(s * k, k, bs);
      unsigned short h = f2bf(u); h1[j] = h; l1[j] = f2bf(u - bf2f(h));
      unsigned short g = f2bf(w); h2[j] = g; l2[j] = f2bf(w - bf2f(g));
    }
    const int s = cb >> 3;
    *reinterpret_cast<u16x8*>(&Uh[((size_t)s * HW + p) * 8])       = h1;
    *reinterpret_cast<u16x8*>(&Ul[((size_t)s * HW + p) * 8])       = l1;
    *reinterpret_cast<u16x8*>(&Uh[((size_t)(s + 8) * HW + p) * 8]) = h2;
    *reinterpret_cast<u16x8*>(&Ul[((size_t)(s + 8) * HW + p) * 8]) = l2;
  }
  bsq[p] = bs;
}

// ---------------------------------------------------------------------------
// Sim kernel: 128 pixels x 7-window strip per block (448 blocks).
// ---------------------------------------------------------------------------
__global__ __launch_bounds__(256, 2)
void k_sim(const unsigned short* __restrict__ Uh, const unsigned short* __restrict__ Ul,
           const unsigned short* __restrict__ Bh,
           const float* __restrict__ bsq, const float* __restrict__ shr_s,
           float* __restrict__ pmax)
{
  __shared__ char smem[65536] __attribute__((aligned(16)));
  const int tid = threadIdx.x;
  const int wid = tid >> 6, lane = tid & 63;
  const int lr = lane & 15, lg = lane >> 4;
  const int pb = blockIdx.x % 14, st = blockIdx.x / 14;
  const int pw = pb * 128 + wid * 32;
  const int w0 = st * WPS;

  bf16x8 a0h[4], a0l[4], a1h[4], a1l[4];
  #pragma unroll
  for (int t = 0; t < 4; ++t) {
    const size_t e0 = ((size_t)(t * 4 + lg) * HW + pw + lr) * 8;
    const size_t e1 = e0 + 16 * 8;
    a0h[t] = *reinterpret_cast<const bf16x8*>(&Uh[e0]);
    a0l[t] = *reinterpret_cast<const bf16x8*>(&Ul[e0]);
    a1h[t] = *reinterpret_cast<const bf16x8*>(&Uh[e1]);
    a1l[t] = *reinterpret_cast<const bf16x8*>(&Ul[e1]);
  }
  float bq[2][4];
  #pragma unroll
  for (int pt = 0; pt < 2; ++pt)
    #pragma unroll
    for (int r = 0; r < 4; ++r) bq[pt][r] = bsq[pw + pt * 16 + 4 * lg + r];

  auto stage = [&](int buf, int i) {
    const int n0 = (w0 + i) * 128;
    #pragma unroll
    for (int j = 0; j < 8; ++j) {
      const int idx = j * 256 + tid;
      const int s = idx >> 7, rr = idx & 127;
      gl_lds16((const char*)Bh + ((size_t)s * NMEM + n0 + rr) * 16,
               smem + buf * 32768 + idx * 16);
    }
  };

  stage(0, 0);
  int buf = 0;
  for (int i = 0; i < WPS; ++i) {
    __syncthreads();
    if (i + 1 < WPS) stage(buf ^ 1, i + 1);

    f32x4 acc[2][8];
    #pragma unroll
    for (int a = 0; a < 2; ++a)
      #pragma unroll
      for (int b = 0; b < 8; ++b) acc[a][b] = (f32x4){0.f, 0.f, 0.f, 0.f};

    const short* lb = (const short*)(smem + buf * 32768);
    #pragma unroll
    for (int t = 0; t < 4; ++t) {
      #pragma unroll
      for (int nt = 0; nt < 8; ++nt) {
        bf16x8 bh = *reinterpret_cast<const bf16x8*>(
            &lb[((t * 4 + lg) * 128 + nt * 16 + lr) * 8]);
        acc[0][nt] = __builtin_amdgcn_mfma_f32_16x16x32_bf16(a0h[t], bh, acc[0][nt], 0, 0, 0);
        acc[0][nt] = __builtin_amdgcn_mfma_f32_16x16x32_bf16(a0l[t], bh, acc[0][nt], 0, 0, 0);
        acc[1][nt] = __builtin_amdgcn_mfma_f32_16x16x32_bf16(a1h[t], bh, acc[1][nt], 0, 0, 0);
        acc[1][nt] = __builtin_amdgcn_mfma_f32_16x16x32_bf16(a1l[t], bh, acc[1][nt], 0, 0, 0);
      }
    }

    const int wgl = w0 + i;
    const int n0 = wgl * 128;
    float shv[8];
    #pragma unroll
    for (int nt = 0; nt < 8; ++nt) shv[nt] = shr_s[n0 + nt * 16 + lr];
    #pragma unroll
    for (int pt = 0; pt < 2; ++pt) {
      #pragma unroll
      for (int r = 0; r < 4; ++r) {
        float mx = -INFINITY;
        #pragma unroll
        for (int nt = 0; nt < 8; ++nt)
          mx = fmaxf(mx, (acc[pt][nt][r] - bq[pt][r]) * shv[nt]);
        pmax[(size_t)(pw + pt * 16 + 4 * lg + r) * NCHUNK + wgl * 16 + lr] = mx;
      }
    }
    buf ^= 1;
  }
}

// ---------------------------------------------------------------------------
// Shared-memory union for the fused select/transpose kernel (~34 KB)
// ---------------------------------------------------------------------------
struct SelS {
  int            hist[2][BINS];  // 16 KB, 2 copies (wave parity) vs hot bins
  unsigned short chl[NCHUNK];    // 7 KB
  float          vcache[VCACHE]; // 4 KB
  float          sqk[64], sqs[64];
  unsigned       au[64];
  int            ai[64];
  unsigned       bu[BCAP];       // 2 KB
  int            bi[BCAP];       // 2 KB
  float          fv[32];
  int            fi[32];
  float          ew[32];
  int            lsum[256];
  int            wsum[4];
  int            sB, sNA, cA, cB, sSC;
  float          sSum;
};
union SMemU {
  SelS  sel;
  float tt[64][65];              // 16.6 KB transpose tile
};

// ---------------------------------------------------------------------------
// crossing finder over hist[0]+hist[1]: smallest bin B with
// prefix(<B) < target <= prefix(<=B). Writes s.sB, s.sNA (=prefix(<B)).
// ---------------------------------------------------------------------------
__device__ __forceinline__ void find_cross(SelS& s, int tid, int target)
{
  const int base = tid * (BINS / 256);   // 8 bins/thread
  int hv[8];
  int ls = 0;
  #pragma unroll
  for (int k = 0; k < 8; ++k) {
    hv[k] = s.hist[0][base + k] + s.hist[1][base + k];
    ls += hv[k];
  }
  s.lsum[tid] = ls;
  __syncthreads();
  int lane = tid & 63, wv = tid >> 6;
  int v = ls;
  #pragma unroll
  for (int off = 1; off < 64; off <<= 1) {
    int t = __shfl_up(v, off);
    if (lane >= off) v += t;
  }
  if (lane == 63) s.wsum[wv] = v;
  __syncthreads();
  int wo = 0;
  for (int k = 0; k < wv; ++k) wo += s.wsum[k];
  int run = wo + v - ls;
  #pragma unroll
  for (int k = 0; k < 8; ++k) {
    if (run < target && run + hv[k] >= target) { s.sB = base + k; s.sNA = run; }
    run += hv[k];
  }
  __syncthreads();
}

__device__ __forceinline__ void clear_hist(SelS& s, int tid)
{
  #pragma unroll
  for (int k = 0; k < 2 * BINS / 256; ++k) (&s.hist[0][0])[tid + 256 * k] = 0;
}

// ---------------------------------------------------------------------------
// Fused kernel: select blocks (per-pixel exact top-30 via chunk-max pruning,
// two-level histogram refinement, exact fp32 recompute) interleaved 1:4 with
// transpose blocks (mem_value fp32 [1024][N] -> mvT fp16 [N][1024]).
// ---------------------------------------------------------------------------
__global__ __launch_bounds__(256, 4)
void k_selT(const float* __restrict__ pmax, const float* __restrict__ mkT,
            const float* __restrict__ q_key, const float* __restrict__ q_sel,
            const float* __restrict__ shr_s,
            float* __restrict__ wgt, int* __restrict__ widx,
            const float* __restrict__ mv, _Float16* __restrict__ mvT)
{
  __shared__ SMemU sm;
  const int tid = threadIdx.x;

  int pix = -1, tb = -1;
  if (gridDim.x > HW) {
    const int g = blockIdx.x / 5, r = blockIdx.x % 5;
    if (r == 0) pix = g; else tb = g * 4 + (r - 1);
  } else {
    pix = blockIdx.x;
  }

  if (tb >= 0) {
    // ---- transpose block: 64n x 64ch fp32 -> fp16
    const int n0 = (tb % 448) * 64, ch0 = (tb / 448) * 64;
    for (int i = tid; i < 64 * 16; i += 256) {
      int r = i >> 4, c4 = (i & 15) << 2;
      float4 v = *reinterpret_cast<const float4*>(&mv[(size_t)(ch0 + r) * NMEM + n0 + c4]);
      sm.tt[r][c4] = v.x; sm.tt[r][c4 + 1] = v.y;
      sm.tt[r][c4 + 2] = v.z; sm.tt[r][c4 + 3] = v.w;
    }
    __syncthreads();
    for (int i = tid; i < 64 * 16; i += 256) {
      int r = i >> 4, c4 = (i & 15) << 2;
      h4 hv = {(_Float16)sm.tt[c4][r], (_Float16)sm.tt[c4 + 1][r],
               (_Float16)sm.tt[c4 + 2][r], (_Float16)sm.tt[c4 + 3][r]};
      *reinterpret_cast<h4*>(&mvT[(size_t)(n0 + r) * 1024 + ch0 + c4]) = hv;
    }
    return;
  }

  SelS& s = sm.sel;
  const int hc = (tid >> 6) & 1;     // histogram copy by wave parity

  if (tid < 64) {
    s.sqk[tid] = q_key[(size_t)tid * HW + pix];
    s.sqs[tid] = q_sel[(size_t)tid * HW + pix];
  }
  clear_hist(s, tid);
  if (tid == 0) { s.sSC = 0; s.cA = 0; s.cB = 0; }
  __syncthreads();

  // ---- stage 1, level 1: histogram of chunk maxima (key >> L1SHIFT)
  float m[NCHUNK / 256];
  const float* pm = pmax + (size_t)pix * NCHUNK;
  #pragma unroll
  for (int j = 0; j < NCHUNK / 256; ++j) m[j] = pm[tid + 256 * j];
  #pragma unroll
  for (int j = 0; j < NCHUNK / 256; ++j)
    atomicAdd(&s.hist[hc][fkey(m[j]) >> L1SHIFT], 1);
  __syncthreads();
  find_cross(s, tid, CTARGET);
  const int B1 = s.sB, nA1 = s.sNA;
  clear_hist(s, tid);
  __syncthreads();

  // ---- stage 1, level 2: sub-histogram of bin-B1 entries (next 11 bits)
  #pragma unroll
  for (int j = 0; j < NCHUNK / 256; ++j) {
    unsigned u = fkey(m[j]);
    if ((int)(u >> L1SHIFT) == B1)
      atomicAdd(&s.hist[hc][(u >> L2SHIFT) & (BINS - 1)], 1);
  }
  __syncthreads();
  find_cross(s, tid, CTARGET - nA1);
  const int Bs1 = s.sB;

  // ---- survivors: bin < B1, or bin == B1 && sub <= Bs1 (inclusive margin)
  #pragma unroll
  for (int j = 0; j < NCHUNK / 256; ++j) {
    unsigned u = fkey(m[j]);
    int bin = (int)(u >> L1SHIFT);
    bool keep = (bin < B1) ||
                (bin == B1 && (int)((u >> L2SHIFT) & (BINS - 1)) <= Bs1);
    if (keep) {
      int k = atomicAdd(&s.sSC, 1);
      s.chl[k] = (unsigned short)(tid + 256 * j);
    }
  }
  __syncthreads();
  const int NC = s.sSC * 8;
  clear_hist(s, tid);
  __syncthreads();

  const float4* sqk4 = reinterpret_cast<const float4*>(s.sqk);
  const float4* sqs4 = reinterpret_cast<const float4*>(s.sqs);

  // ---- stage 2 pass X: exact fp32 sims of candidates + L1 histogram
  for (int c = tid; c < NC; c += 256) {
    const int cc = s.chl[c >> 3];
    const int n = ((cc >> 4) << 7) + (cc & 15) + ((c & 7) << 4);
    const float4* mr = reinterpret_cast<const float4*>(mkT + (size_t)n * 64);
    float sv = 0.f;
    #pragma unroll
    for (int j = 0; j < 16; ++j) {
      float4 q = mr[j], k4 = sqk4[j], s4 = sqs4[j];
      float d0 = q.x - k4.x, d1 = q.y - k4.y, d2 = q.z - k4.z, d3 = q.w - k4.w;
      sv = fmaf(s4.x * d0, d0, sv); sv = fmaf(s4.y * d1, d1, sv);
      sv = fmaf(s4.z * d2, d2, sv); sv = fmaf(s4.w * d3, d3, sv);
    }
    float v = -sv * shr_s[n];
    if (c < VCACHE) s.vcache[c] = v;
    atomicAdd(&s.hist[hc][fkey(v) >> L1SHIFT], 1);
  }
  __syncthreads();
  find_cross(s, tid, TOPK);
  const int B2 = s.sB, nA2 = s.sNA;
  clear_hist(s, tid);
  __syncthreads();

  // ---- stage 2, level 2: sub-histogram of bin-B2 candidates
  for (int c = tid; c < NC; c += 256) {
    float v;
    if (c < VCACHE) v = s.vcache[c];
    else {
      const int cc = s.chl[c >> 3];
      const int n = ((cc >> 4) << 7) + (cc & 15) + ((c & 7) << 4);
      const float4* mr = reinterpret_cast<const float4*>(mkT + (size_t)n * 64);
      float sv = 0.f;
      #pragma unroll
      for (int j = 0; j < 16; ++j) {
        float4 q = mr[j], k4 = sqk4[j], s4 = sqs4[j];
        float d0 = q.x - k4.x, d1 = q.y - k4.y, d2 = q.z - k4.z, d3 = q.w - k4.w;
        sv = fmaf(s4.x * d0, d0, sv); sv = fmaf(s4.y * d1, d1, sv);
        sv = fmaf(s4.z * d2, d2, sv); sv = fmaf(s4.w * d3, d3, sv);
      }
      v = -sv * shr_s[n];
    }
    unsigned u = fkey(v);
    if ((int)(u >> L1SHIFT) == B2)
      atomicAdd(&s.hist[hc][(u >> L2SHIFT) & (BINS - 1)], 1);
  }
  __syncthreads();
  find_cross(s, tid, TOPK - nA2);
  const int Bs2 = s.sB;

  // ---- stage 2 pass Y: collect sure top-30 + sub-boundary rank-cut
  for (int c = tid; c < NC; c += 256) {
    float v;
    if (c < VCACHE) v = s.vcache[c];
    else {
      const int cc = s.chl[c >> 3];
      const int n = ((cc >> 4) << 7) + (cc & 15) + ((c & 7) << 4);
      const float4* mr = reinterpret_cast<const float4*>(mkT + (size_t)n * 64);
      float sv = 0.f;
      #pragma unroll
      for (int j = 0; j < 16; ++j) {
        float4 q = mr[j], k4 = sqk4[j], s4 = sqs4[j];
        float d0 = q.x - k4.x, d1 = q.y - k4.y, d2 = q.z - k4.z, d3 = q.w - k4.w;
        sv = fmaf(s4.x * d0, d0, sv); sv = fmaf(s4.y * d1, d1, sv);
        sv = fmaf(s4.z * d2, d2, sv); sv = fmaf(s4.w * d3, d3, sv);
      }
      v = -sv * shr_s[n];
    }
    const int cc = s.chl[c >> 3];
    const int n = ((cc >> 4) << 7) + (cc & 15) + ((c & 7) << 4);
    unsigned u = fkey(v);
    int bin = (int)(u >> L1SHIFT);
    if (bin < B2) {
      int k = atomicAdd(&s.cA, 1); s.au[k] = u; s.ai[k] = n;
    } else if (bin == B2) {
      int sub = (int)((u >> L2SHIFT) & (BINS - 1));
      if (sub < Bs2)       { int k = atomicAdd(&s.cA, 1); s.au[k] = u; s.ai[k] = n; }
      else if (sub == Bs2) { int k = atomicAdd(&s.cB, 1); if (k < BCAP) { s.bu[k] = u; s.bi[k] = n; } }
    }
  }
  __syncthreads();
  {
    const int nAv = s.cA, mm = (s.cB < BCAP ? s.cB : BCAP), need = TOPK - nAv;
    for (int t = tid; t < mm; t += 256) {
      unsigned u = s.bu[t]; int id = s.bi[t];
      int r = 0;
      for (int k2 = 0; k2 < mm; ++k2) {
        unsigned uk = s.bu[k2];
        r += (uk < u) || (uk == u && s.bi[k2] < id);
      }
      if (r < need) { s.au[nAv + r] = u; s.ai[nAv + r] = id; }
    }
  }
  __syncthreads();

  // ---- deterministic ordering of the 30 + softmax
  if (tid < TOPK) {
    unsigned u = s.au[tid]; int id = s.ai[tid];
    int r = 0;
    for (int k2 = 0; k2 < TOPK; ++k2) {
      unsigned uk = s.au[k2];
      r += (uk < u) || (uk == u && s.ai[k2] < id);
    }
    s.fv[r] = -__uint_as_float(u); s.fi[r] = id;
  }
  __syncthreads();
  if (tid < 32) {
    float e = (tid < TOPK) ? expf(s.fv[tid]) : 0.f;
    if (tid < TOPK) s.ew[tid] = e;
    float ss = e;
    #pragma unroll
    for (int off = 16; off > 0; off >>= 1) ss += __shfl_down(ss, off);
    if (tid == 0) s.sSum = ss;
  }
  __syncthreads();
  if (tid < TOPK) {
    wgt [(size_t)pix * 32 + tid] = s.ew[tid] / s.sSum;
    widx[(size_t)pix * 32 + tid] = s.fi[tid];
  }
}

// ---------------------------------------------------------------------------
// Standalone fp16 transpose (fallback, overlay mode)
// ---------------------------------------------------------------------------
__global__ __launch_bounds__(256)
void k_transpose_h(const float* __restrict__ mv, _Float16* __restrict__ mvT)
{
  __shared__ float t[64][65];
  const int n0 = blockIdx.x * 64, ch0 = blockIdx.y * 64;
  const int tid = threadIdx.x;
  for (int i = tid; i < 64 * 16; i += 256) {
    int r = i >> 4, c4 = (i & 15) << 2;
    float4 v = *reinterpret_cast<const float4*>(&mv[(size_t)(ch0 + r) * NMEM + n0 + c4]);
    t[r][c4] = v.x; t[r][c4 + 1] = v.y; t[r][c4 + 2] = v.z; t[r][c4 + 3] = v.w;
  }
  __syncthreads();
  for (int i = tid; i < 64 * 16; i += 256) {
    int r = i >> 4, c4 = (i & 15) << 2;
    h4 hv = {(_Float16)t[c4][r], (_Float16)t[c4 + 1][r],
             (_Float16)t[c4 + 2][r], (_Float16)t[c4 + 3][r]};
    *reinterpret_cast<h4*>(&mvT[(size_t)(n0 + r) * 1024 + ch0 + c4]) = hv;
  }
}

// ---------------------------------------------------------------------------
// Gather (fp16 source): out[ch][p] = sum_k w[p][k] * mvT[idx[p][k]][ch]
// ---------------------------------------------------------------------------
__global__ __launch_bounds__(256)
void k_gather_h(const _Float16* __restrict__ mvT, const float* __restrict__ wgt,
                const int* __restrict__ widx, float* __restrict__ out)
{
  __shared__ float sw[8][TOPK];
  __shared__ int   si[8][TOPK];
  __shared__ float sbuf[256][9];
  const int p0 = blockIdx.x * 8, chg = blockIdx.y * 256;
  const int tid = threadIdx.x;

  for (int i = tid; i < 8 * TOPK; i += 256) {
    int q = i / TOPK, k = i - q * TOPK;
    sw[q][k] = wgt [(size_t)(p0 + q) * 32 + k];
    si[q][k] = widx[(size_t)(p0 + q) * 32 + k];
  }
  __syncthreads();

  const int ch = chg + tid;
  #pragma unroll 2
  for (int q = 0; q < 8; ++q) {
    float a = 0.f;
    #pragma unroll
    for (int k = 0; k < TOPK; ++k)
      a = fmaf(sw[q][k], (float)mvT[(size_t)si[q][k] * 1024 + ch], a);
    sbuf[tid][q] = a;
  }
  __syncthreads();

  for (int i = tid; i < 256 * 8; i += 256) {
    int cl = i >> 3, q = i & 7;
    out[(size_t)(chg + cl) * HW + p0 + q] = sbuf[cl][q];
  }
}

// ---------------------------------------------------------------------------
// Gather (fp32 strided source, raw fallback)
// ---------------------------------------------------------------------------
__global__ __launch_bounds__(256)
void k_gather_f(const float* __restrict__ src, const float* __restrict__ wgt,
                const int* __restrict__ widx, float* __restrict__ out,
                long n_stride, long ch_stride)
{
  __shared__ float sw[8][TOPK];
  __shared__ int   si[8][TOPK];
  __shared__ float sbuf[256][9];
  const int p0 = blockIdx.x * 8, chg = blockIdx.y * 256;
  const int tid = threadIdx.x;

  for (int i = tid; i < 8 * TOPK; i += 256) {
    int q = i / TOPK, k = i - q * TOPK;
    sw[q][k] = wgt [(size_t)(p0 + q) * 32 + k];
    si[q][k] = widx[(size_t)(p0 + q) * 32 + k];
  }
  __syncthreads();

  const int ch = chg + tid;
  #pragma unroll 2
  for (int q = 0; q < 8; ++q) {
    float a = 0.f;
    #pragma unroll
    for (int k = 0; k < TOPK; ++k)
      a = fmaf(sw[q][k], src[(size_t)si[q][k] * n_stride + (size_t)ch * ch_stride], a);
    sbuf[tid][q] = a;
  }
  __syncthreads();

  for (int i = tid; i < 256 * 8; i += 256) {
    int cl = i >> 3, q = i & 7;
    out[(size_t)(chg + cl) * HW + p0 + q] = sbuf[cl][q];
  }
}

// ---------------------------------------------------------------------------
extern "C" void kernel_launch(void* const* d_in, const int* in_sizes, int n_in,
                              void* d_out, int out_size, void* d_ws, size_t ws_size,
                              hipStream_t stream)
{
  (void)in_sizes; (void)n_in; (void)out_size;
  const float* q_key     = (const float*)d_in[0];
  const float* q_sel     = (const float*)d_in[1];
  const float* mem_key   = (const float*)d_in[2];
  const float* mem_shr   = (const float*)d_in[3];
  const float* mem_value = (const float*)d_in[4];
  float* out = (float*)d_out;

  char* ws = (char*)d_ws;
  size_t off = 0;
  auto alloc = [&](size_t b) { size_t c = off; off = (off + b + 255) & ~(size_t)255; return c; };
  size_t o_w   = alloc((size_t)HW * 32 * 4);
  size_t o_wi  = alloc((size_t)HW * 32 * 4);
  size_t o_pr  = off;                              // overlay point (fallback)
  size_t o_bh  = alloc((size_t)NMEM * 128 * 2);    // 7.34 MB
  size_t o_uh  = alloc((size_t)HW * 128 * 2);
  size_t o_ul  = alloc((size_t)HW * 128 * 2);
  size_t o_bsq = alloc((size_t)HW * 4);
  size_t o_shr = alloc((size_t)NMEM * 4);
  size_t o_mkT = alloc((size_t)NMEM * 64 * 4);     // 7.34 MB
  size_t o_pm  = alloc((size_t)HW * NCHUNK * 4);   // 25.7 MB
  size_t o_end = off;

  float*          wg   = (float*)(ws + o_w);
  int*            wi   = (int*)  (ws + o_wi);
  unsigned short* Bh   = (unsigned short*)(ws + o_bh);
  unsigned short* Uh   = (unsigned short*)(ws + o_uh);
  unsigned short* Ul   = (unsigned short*)(ws + o_ul);
  float*          bsq  = (float*)(ws + o_bsq);
  float*          shr  = (float*)(ws + o_shr);
  float*          mkT  = (float*)(ws + o_mkT);
  float*          pmx  = (float*)(ws + o_pm);

  const size_t mvh_sz = (size_t)NMEM * 1024 * 2;   // 58.7 MB fp16

  k_prep_b<<<NMEM / 256, 256, 0, stream>>>(mem_key, mem_shr, Bh, mkT, shr);
  k_prep_u<<<HW / 256, 256, 0, stream>>>(q_key, q_sel, Uh, Ul, bsq);
  k_sim<<<SIMB, 256, 0, stream>>>(Uh, Ul, Bh, bsq, shr, pmx);

  if (ws_size >= o_end + mvh_sz) {
    // fused: select (1792) + transpose (7168) interleaved 1:4
    _Float16* mvT = (_Float16*)(ws + o_end);
    k_selT<<<HW * 5, 256, 0, stream>>>(pmx, mkT, q_key, q_sel, shr,
                                       wg, wi, mem_value, mvT);
    k_gather_h<<<dim3(HW / 8, 4), 256, 0, stream>>>(mvT, wg, wi, out);
  } else {
    // fallback: select only, then transpose into overlay region (or raw)
    k_selT<<<HW, 256, 0, stream>>>(pmx, mkT, q_key, q_sel, shr,
                                   wg, wi, mem_value, nullptr);
    if (ws_size >= o_pr + mvh_sz) {
      _Float16* mvT = (_Float16*)(ws + o_pr);      // Bh..pmx dead after select
      k_transpose_h<<<dim3(NMEM / 64, 16), 256, 0, stream>>>(mem_value, mvT);
      k_gather_h<<<dim3(HW / 8, 4), 256, 0, stream>>>(mvT, wg, wi, out);
    } else {
      k_gather_f<<<dim3(HW / 8, 4), 256, 0, stream>>>(
          mem_value, wg, wi, out, 1, NMEM);
    }
  }
}

// Round 11
// 169.683 us; speedup vs baseline: 1.1766x; 1.1766x over previous
//
#include <hip/hip_runtime.h>
#include <math.h>

#define HW      1792
#define NMEM    28672
#define NCHUNK  3584          // NMEM/8 chunks of 8
#define TOPK    30
#define CTARGET 64
#define SCAP    80            // survivor chunk cap (640 candidates)
#define SIMB    448           // 14 p-blocks(128px) x 32 strips
#define WPS     7             // 128-n windows per strip

typedef __attribute__((ext_vector_type(8))) short bf16x8;
typedef __attribute__((ext_vector_type(8))) unsigned short u16x8;
typedef __attribute__((ext_vector_type(4))) float f32x4;
typedef __attribute__((ext_vector_type(4))) _Float16 h4;

static __device__ __forceinline__ unsigned short f2bf(float v) {
  unsigned b = __float_as_uint(v);
  return (unsigned short)((b + 0x7FFFu + ((b >> 16) & 1u)) >> 16);
}
static __device__ __forceinline__ float bf2f(unsigned short h) {
  return __uint_as_float(((unsigned)h) << 16);
}
static __device__ __forceinline__ unsigned fkey(float v) {
  return __float_as_uint(-v) & 0x7FFFFFFFu;
}
static __device__ __forceinline__ void gl_lds16(const void* g, void* l) {
  __builtin_amdgcn_global_load_lds(
      (const __attribute__((address_space(1))) unsigned*)g,
      (__attribute__((address_space(3))) unsigned*)l, 16, 0, 0);
}
// wave-scope LDS handoff: drain ds ops + block compiler reordering
#define WSYNC() do { asm volatile("s_waitcnt lgkmcnt(0)" ::: "memory"); \
                     __builtin_amdgcn_wave_barrier(); } while (0)

// ---------------------------------------------------------------------------
// Prep B: Bh[s][n][8] bf16-hi (s=0..7: mk, s=8..15: mk^2); mkT[n][64] fp32;
// shr_s = mem_shr/8.
// ---------------------------------------------------------------------------
__global__ __launch_bounds__(256)
void k_prep_b(const float* __restrict__ mk, const float* __restrict__ shr_in,
              unsigned short* __restrict__ Bh,
              float* __restrict__ mkT, float* __restrict__ shr_s)
{
  const int n = blockIdx.x * 256 + threadIdx.x;
  shr_s[n] = shr_in[n] * 0.125f;
  for (int cb = 0; cb < 64; cb += 8) {
    u16x8 h1, h2;
    float vv[8];
    #pragma unroll
    for (int j = 0; j < 8; ++j) {
      float v = mk[(size_t)(cb + j) * NMEM + n];
      vv[j] = v;
      h1[j] = f2bf(v);
      h2[j] = f2bf(v * v);
    }
    const int s = cb >> 3;
    *reinterpret_cast<u16x8*>(&Bh[((size_t)s * NMEM + n) * 8])       = h1;
    *reinterpret_cast<u16x8*>(&Bh[((size_t)(s + 8) * NMEM + n) * 8]) = h2;
    *reinterpret_cast<float4*>(&mkT[(size_t)n * 64 + cb])     = make_float4(vv[0], vv[1], vv[2], vv[3]);
    *reinterpret_cast<float4*>(&mkT[(size_t)n * 64 + cb + 4]) = make_float4(vv[4], vv[5], vv[6], vv[7]);
  }
}

// ---------------------------------------------------------------------------
// Prep U: Uh/Ul[s][p][8] bf16 hi/lo. s=0..7: 2*qk*qs, s=8..15: -qs. bsq[p].
// ---------------------------------------------------------------------------
__global__ __launch_bounds__(256)
void k_prep_u(const float* __restrict__ q_key, const float* __restrict__ q_sel,
              unsigned short* __restrict__ Uh, unsigned short* __restrict__ Ul,
              float* __restrict__ bsq)
{
  const int p = blockIdx.x * 256 + threadIdx.x;
  float bs = 0.f;
  for (int cb = 0; cb < 64; cb += 8) {
    u16x8 h1, l1, h2, l2;
    #pragma unroll
    for (int j = 0; j < 8; ++j) {
      int c = cb + j;
      float k = q_key[(size_t)c * HW + p];
      float s = q_sel[(size_t)c * HW + p];
      float u = 2.f * k * s;
      float w = -s;
      bs = fmaf(s * k, k, bs);
      unsigned short h = f2bf(u); h1[j] = h; l1[j] = f2bf(u - bf2f(h));
      unsigned short g = f2bf(w); h2[j] = g; l2[j] = f2bf(w - bf2f(g));
    }
    const int s = cb >> 3;
    *reinterpret_cast<u16x8*>(&Uh[((size_t)s * HW + p) * 8])       = h1;
    *reinterpret_cast<u16x8*>(&Ul[((size_t)s * HW + p) * 8])       = l1;
    *reinterpret_cast<u16x8*>(&Uh[((size_t)(s + 8) * HW + p) * 8]) = h2;
    *reinterpret_cast<u16x8*>(&Ul[((size_t)(s + 8) * HW + p) * 8]) = l2;
  }
  bsq[p] = bs;
}

// ---------------------------------------------------------------------------
// Sim kernel: 128 pixels x 7-window strip per block (448 blocks). Unchanged.
// ---------------------------------------------------------------------------
__global__ __launch_bounds__(256, 2)
void k_sim(const unsigned short* __restrict__ Uh, const unsigned short* __restrict__ Ul,
           const unsigned short* __restrict__ Bh,
           const float* __restrict__ bsq, const float* __restrict__ shr_s,
           float* __restrict__ pmax)
{
  __shared__ char smem[65536] __attribute__((aligned(16)));
  const int tid = threadIdx.x;
  const int wid = tid >> 6, lane = tid & 63;
  const int lr = lane & 15, lg = lane >> 4;
  const int pb = blockIdx.x % 14, st = blockIdx.x / 14;
  const int pw = pb * 128 + wid * 32;
  const int w0 = st * WPS;

  bf16x8 a0h[4], a0l[4], a1h[4], a1l[4];
  #pragma unroll
  for (int t = 0; t < 4; ++t) {
    const size_t e0 = ((size_t)(t * 4 + lg) * HW + pw + lr) * 8;
    const size_t e1 = e0 + 16 * 8;
    a0h[t] = *reinterpret_cast<const bf16x8*>(&Uh[e0]);
    a0l[t] = *reinterpret_cast<const bf16x8*>(&Ul[e0]);
    a1h[t] = *reinterpret_cast<const bf16x8*>(&Uh[e1]);
    a1l[t] = *reinterpret_cast<const bf16x8*>(&Ul[e1]);
  }
  float bq[2][4];
  #pragma unroll
  for (int pt = 0; pt < 2; ++pt)
    #pragma unroll
    for (int r = 0; r < 4; ++r) bq[pt][r] = bsq[pw + pt * 16 + 4 * lg + r];

  auto stage = [&](int buf, int i) {
    const int n0 = (w0 + i) * 128;
    #pragma unroll
    for (int j = 0; j < 8; ++j) {
      const int idx = j * 256 + tid;
      const int s = idx >> 7, rr = idx & 127;
      gl_lds16((const char*)Bh + ((size_t)s * NMEM + n0 + rr) * 16,
               smem + buf * 32768 + idx * 16);
    }
  };

  stage(0, 0);
  int buf = 0;
  for (int i = 0; i < WPS; ++i) {
    __syncthreads();
    if (i + 1 < WPS) stage(buf ^ 1, i + 1);

    f32x4 acc[2][8];
    #pragma unroll
    for (int a = 0; a < 2; ++a)
      #pragma unroll
      for (int b = 0; b < 8; ++b) acc[a][b] = (f32x4){0.f, 0.f, 0.f, 0.f};

    const short* lb = (const short*)(smem + buf * 32768);
    #pragma unroll
    for (int t = 0; t < 4; ++t) {
      #pragma unroll
      for (int nt = 0; nt < 8; ++nt) {
        bf16x8 bh = *reinterpret_cast<const bf16x8*>(
            &lb[((t * 4 + lg) * 128 + nt * 16 + lr) * 8]);
        acc[0][nt] = __builtin_amdgcn_mfma_f32_16x16x32_bf16(a0h[t], bh, acc[0][nt], 0, 0, 0);
        acc[0][nt] = __builtin_amdgcn_mfma_f32_16x16x32_bf16(a0l[t], bh, acc[0][nt], 0, 0, 0);
        acc[1][nt] = __builtin_amdgcn_mfma_f32_16x16x32_bf16(a1h[t], bh, acc[1][nt], 0, 0, 0);
        acc[1][nt] = __builtin_amdgcn_mfma_f32_16x16x32_bf16(a1l[t], bh, acc[1][nt], 0, 0, 0);
      }
    }

    const int wgl = w0 + i;
    const int n0 = wgl * 128;
    float shv[8];
    #pragma unroll
    for (int nt = 0; nt < 8; ++nt) shv[nt] = shr_s[n0 + nt * 16 + lr];
    #pragma unroll
    for (int pt = 0; pt < 2; ++pt) {
      #pragma unroll
      for (int r = 0; r < 4; ++r) {
        float mx = -INFINITY;
        #pragma unroll
        for (int nt = 0; nt < 8; ++nt)
          mx = fmaxf(mx, (acc[pt][nt][r] - bq[pt][r]) * shv[nt]);
        pmax[(size_t)(pw + pt * 16 + 4 * lg + r) * NCHUNK + wgl * 16 + lr] = mx;
      }
    }
    buf ^= 1;
  }
}

// ---------------------------------------------------------------------------
// Wave-level crossing: logical bin b = lane*16+k stored at phys (k<<6)|lane
// (conflict-free reads). Returns smallest B with prefix(<B) < target <=
// prefix(<=B) and nA = prefix(<B); broadcast to all lanes.
// ---------------------------------------------------------------------------
__device__ __forceinline__ void wave_cross(const int* h, int lane, int target,
                                           int& B, int& nA)
{
  int hv[16]; int ls = 0;
  #pragma unroll
  for (int k = 0; k < 16; ++k) { hv[k] = h[(k << 6) + lane]; ls += hv[k]; }
  int sc = ls;
  #pragma unroll
  for (int off = 1; off < 64; off <<= 1) {
    int t = __shfl_up(sc, off);
    if (lane >= off) sc += t;
  }
  int run = sc - ls;                 // exclusive prefix of this lane's 16 bins
  int myB = -1, mynA = 0;
  #pragma unroll
  for (int k = 0; k < 16; ++k) {
    if (run < target && run + hv[k] >= target) { myB = lane * 16 + k; mynA = run; }
    run += hv[k];
  }
  unsigned long long ball = __ballot(myB >= 0);
  int src = __ffsll((long long)ball) - 1;
  B = __shfl(myB, src); nA = __shfl(mynA, src);
}

// ---------------------------------------------------------------------------
// Select: one pixel per WAVE (4 waves/block, zero __syncthreads).
// Stage 1: two-level wave histogram on chunk maxima -> ~64-80 survivor chunks.
// Stage 2: exact fp32 sims of survivors -> packed 64-bit keys in LDS.
// Stage 3: 30 wave-argmax rounds (exact, (value, lower-idx) tie-break),
// softmax, write weights+indices.
// ---------------------------------------------------------------------------
__global__ __launch_bounds__(256, 2)
void k_select(const float* __restrict__ pmax, const float* __restrict__ mkT,
              const float* __restrict__ q_key, const float* __restrict__ q_sel,
              const float* __restrict__ shr_s,
              float* __restrict__ wgt, int* __restrict__ widx)
{
  __shared__ int                hist[4][1024];   // 16 KB (phys-transposed idx)
  __shared__ unsigned long long pk[4][640];      // 20 KB packed (val,idx) keys
  __shared__ short              slist[4][SCAP];  // survivor chunk ids
  __shared__ float              sqk[4][64], sqs[4][64];

  const int w = threadIdx.x >> 6, lane = threadIdx.x & 63;
  const int pix = blockIdx.x * 4 + w;
  int* h = hist[w];
  unsigned long long* p = pk[w];
  short* sl = slist[w];

  // physical index for logical bin b: spread so crossing reads are stride-64
  auto ph = [](int b) { return ((b & 15) << 6) | (b >> 4); };

  sqk[w][lane] = q_key[(size_t)lane * HW + pix];
  sqs[w][lane] = q_sel[(size_t)lane * HW + pix];

  // ---- load this pixel's 3584 chunk maxima (56/lane, coalesced)
  float m[56];
  const float* pm = pmax + (size_t)pix * NCHUNK;
  #pragma unroll
  for (int j = 0; j < 56; ++j) m[j] = pm[lane + 64 * j];

  // ---- stage 1, L1: 10-bit histogram (key >> 21)
  #pragma unroll
  for (int k = 0; k < 16; ++k) h[lane + 64 * k] = 0;
  WSYNC();
  #pragma unroll
  for (int j = 0; j < 56; ++j) atomicAdd(&h[ph(fkey(m[j]) >> 21)], 1);
  WSYNC();
  int B1, nA1;
  wave_cross(h, lane, CTARGET, B1, nA1);

  // ---- stage 1, L2: refine boundary bin over key bits 11..20
  #pragma unroll
  for (int k = 0; k < 16; ++k) h[lane + 64 * k] = 0;
  WSYNC();
  #pragma unroll
  for (int j = 0; j < 56; ++j) {
    unsigned u = fkey(m[j]);
    if ((int)(u >> 21) == B1) atomicAdd(&h[ph((u >> 11) & 1023)], 1);
  }
  WSYNC();
  int Bs1, nAs1;
  wave_cross(h, lane, CTARGET - nA1, Bs1, nAs1);

  // ---- survivors (ballot-compacted): bin<B1 or (bin==B1 && sub<=Bs1)
  int nsurv = 0;
  #pragma unroll
  for (int j = 0; j < 56; ++j) {
    unsigned u = fkey(m[j]);
    int bin = (int)(u >> 21);
    bool keep = (bin < B1) || (bin == B1 && (int)((u >> 11) & 1023) <= Bs1);
    unsigned long long ball = __ballot(keep);
    if (keep) {
      int pos = nsurv + __popcll(ball & ((1ull << lane) - 1ull));
      if (pos < SCAP) sl[pos] = (short)(lane + 64 * j);
    }
    nsurv += __popcll(ball);
  }
  nsurv = (nsurv < SCAP) ? nsurv : SCAP;
  const int NC = nsurv * 8;

  // ---- stage 2: exact fp32 sims -> packed keys (max=best, tie->lower n)
  #pragma unroll
  for (int t = 0; t < 10; ++t) p[lane + (t << 6)] = 0ull;
  WSYNC();
  const float4* k4p = reinterpret_cast<const float4*>(sqk[w]);
  const float4* s4p = reinterpret_cast<const float4*>(sqs[w]);
  for (int c = lane; c < NC; c += 64) {
    const int cc = sl[c >> 3];
    const int n = ((cc >> 4) << 7) + (cc & 15) + ((c & 7) << 4);
    const float4* mr = reinterpret_cast<const float4*>(mkT + (size_t)n * 64);
    float a0 = 0.f, a1 = 0.f, a2 = 0.f, a3 = 0.f;
    #pragma unroll
    for (int j = 0; j < 16; j += 4) {
      #pragma unroll
      for (int jj = 0; jj < 4; ++jj) {
        float4 q = mr[j + jj], kk = k4p[j + jj], ss = s4p[j + jj];
        float d0 = q.x - kk.x, d1 = q.y - kk.y, d2 = q.z - kk.z, d3 = q.w - kk.w;
        float pj = fmaf(ss.x * d0, d0,
                   fmaf(ss.y * d1, d1,
                   fmaf(ss.z * d2, d2, ss.w * d3 * d3)));
        if (jj == 0) a0 += pj; else if (jj == 1) a1 += pj;
        else if (jj == 2) a2 += pj; else a3 += pj;
      }
    }
    float v = -((a0 + a1) + (a2 + a3)) * shr_s[n];
    p[c] = ((unsigned long long)(0x7FFFFFFFu - fkey(v)) << 32) |
           (unsigned long long)(0xFFFFFFFFu - (unsigned)n);
  }
  WSYNC();

  // ---- stage 3: 30 wave-argmax rounds with incremental per-lane best
  unsigned long long bk = 0ull; int bp = -1;
  #pragma unroll
  for (int t = 0; t < 10; ++t) {
    unsigned long long v = p[lane + (t << 6)];
    if (v > bk) { bk = v; bp = lane + (t << 6); }
  }
  float esum = 0.f, myv = 0.f;
  int myn = 0;
  for (int r = 0; r < TOPK; ++r) {
    unsigned long long gk = bk; int gp = bp;
    #pragma unroll
    for (int off = 1; off < 64; off <<= 1) {
      unsigned long long ok = __shfl_xor(gk, off);
      int op = __shfl_xor(gp, off);
      if (ok > gk) { gk = ok; gp = op; }
    }
    float v = -__uint_as_float(0x7FFFFFFFu - (unsigned)(gk >> 32));
    int n = (int)(0xFFFFFFFFu - (unsigned)(gk & 0xFFFFFFFFu));
    esum += expf(v);
    if (lane == r) { myv = v; myn = n; }
    if (lane == (gp & 63)) {
      p[gp] = 0ull;
      asm volatile("s_waitcnt lgkmcnt(0)" ::: "memory");
      bk = 0ull; bp = -1;
      #pragma unroll
      for (int t = 0; t < 10; ++t) {
        unsigned long long vv = p[lane + (t << 6)];
        if (vv > bk) { bk = vv; bp = lane + (t << 6); }
      }
    }
  }
  if (lane < TOPK) {
    wgt [(size_t)pix * 32 + lane] = expf(myv) / esum;
    widx[(size_t)pix * 32 + lane] = myn;
  }
}

// ---------------------------------------------------------------------------
// Transpose: mem_value fp32 [1024][N] -> mvT fp16 [N][1024].
// ---------------------------------------------------------------------------
__global__ __launch_bounds__(256)
void k_transpose_h(const float* __restrict__ mv, _Float16* __restrict__ mvT)
{
  __shared__ float t[64][65];
  const int n0 = blockIdx.x * 64, ch0 = blockIdx.y * 64;
  const int tid = threadIdx.x;
  for (int i = tid; i < 64 * 16; i += 256) {
    int r = i >> 4, c4 = (i & 15) << 2;
    float4 v = *reinterpret_cast<const float4*>(&mv[(size_t)(ch0 + r) * NMEM + n0 + c4]);
    t[r][c4] = v.x; t[r][c4 + 1] = v.y; t[r][c4 + 2] = v.z; t[r][c4 + 3] = v.w;
  }
  __syncthreads();
  for (int i = tid; i < 64 * 16; i += 256) {
    int r = i >> 4, c4 = (i & 15) << 2;
    h4 hv = {(_Float16)t[c4][r], (_Float16)t[c4 + 1][r],
             (_Float16)t[c4 + 2][r], (_Float16)t[c4 + 3][r]};
    *reinterpret_cast<h4*>(&mvT[(size_t)(n0 + r) * 1024 + ch0 + c4]) = hv;
  }
}

// ---------------------------------------------------------------------------
// Gather (fp16 source): out[ch][p] = sum_k w[p][k] * mvT[idx[p][k]][ch]
// ---------------------------------------------------------------------------
__global__ __launch_bounds__(256)
void k_gather_h(const _Float16* __restrict__ mvT, const float* __restrict__ wgt,
                const int* __restrict__ widx, float* __restrict__ out)
{
  __shared__ float sw[8][TOPK];
  __shared__ int   si[8][TOPK];
  __shared__ float sbuf[256][9];
  const int p0 = blockIdx.x * 8, chg = blockIdx.y * 256;
  const int tid = threadIdx.x;

  for (int i = tid; i < 8 * TOPK; i += 256) {
    int q = i / TOPK, k = i - q * TOPK;
    sw[q][k] = wgt [(size_t)(p0 + q) * 32 + k];
    si[q][k] = widx[(size_t)(p0 + q) * 32 + k];
  }
  __syncthreads();

  const int ch = chg + tid;
  #pragma unroll 2
  for (int q = 0; q < 8; ++q) {
    float a = 0.f;
    #pragma unroll
    for (int k = 0; k < TOPK; ++k)
      a = fmaf(sw[q][k], (float)mvT[(size_t)si[q][k] * 1024 + ch], a);
    sbuf[tid][q] = a;
  }
  __syncthreads();

  for (int i = tid; i < 256 * 8; i += 256) {
    int cl = i >> 3, q = i & 7;
    out[(size_t)(chg + cl) * HW + p0 + q] = sbuf[cl][q];
  }
}

// ---------------------------------------------------------------------------
// Gather (fp32 strided source, raw fallback)
// ---------------------------------------------------------------------------
__global__ __launch_bounds__(256)
void k_gather_f(const float* __restrict__ src, const float* __restrict__ wgt,
                const int* __restrict__ widx, float* __restrict__ out,
                long n_stride, long ch_stride)
{
  __shared__ float sw[8][TOPK];
  __shared__ int   si[8][TOPK];
  __shared__ float sbuf[256][9];
  const int p0 = blockIdx.x * 8, chg = blockIdx.y * 256;
  const int tid = threadIdx.x;

  for (int i = tid; i < 8 * TOPK; i += 256) {
    int q = i / TOPK, k = i - q * TOPK;
    sw[q][k] = wgt [(size_t)(p0 + q) * 32 + k];
    si[q][k] = widx[(size_t)(p0 + q) * 32 + k];
  }
  __syncthreads();

  const int ch = chg + tid;
  #pragma unroll 2
  for (int q = 0; q < 8; ++q) {
    float a = 0.f;
    #pragma unroll
    for (int k = 0; k < TOPK; ++k)
      a = fmaf(sw[q][k], src[(size_t)si[q][k] * n_stride + (size_t)ch * ch_stride], a);
    sbuf[tid][q] = a;
  }
  __syncthreads();

  for (int i = tid; i < 256 * 8; i += 256) {
    int cl = i >> 3, q = i & 7;
    out[(size_t)(chg + cl) * HW + p0 + q] = sbuf[cl][q];
  }
}

// ---------------------------------------------------------------------------
extern "C" void kernel_launch(void* const* d_in, const int* in_sizes, int n_in,
                              void* d_out, int out_size, void* d_ws, size_t ws_size,
                              hipStream_t stream)
{
  (void)in_sizes; (void)n_in; (void)out_size;
  const float* q_key     = (const float*)d_in[0];
  const float* q_sel     = (const float*)d_in[1];
  const float* mem_key   = (const float*)d_in[2];
  const float* mem_shr   = (const float*)d_in[3];
  const float* mem_value = (const float*)d_in[4];
  float* out = (float*)d_out;

  char* ws = (char*)d_ws;
  size_t off = 0;
  auto alloc = [&](size_t b) { size_t c = off; off = (off + b + 255) & ~(size_t)255; return c; };
  size_t o_w   = alloc((size_t)HW * 32 * 4);
  size_t o_wi  = alloc((size_t)HW * 32 * 4);
  size_t o_pr  = off;                              // overlay point (fallback)
  size_t o_bh  = alloc((size_t)NMEM * 128 * 2);    // 7.34 MB
  size_t o_uh  = alloc((size_t)HW * 128 * 2);
  size_t o_ul  = alloc((size_t)HW * 128 * 2);
  size_t o_bsq = alloc((size_t)HW * 4);
  size_t o_shr = alloc((size_t)NMEM * 4);
  size_t o_mkT = alloc((size_t)NMEM * 64 * 4);     // 7.34 MB
  size_t o_pm  = alloc((size_t)HW * NCHUNK * 4);   // 25.7 MB
  size_t o_end = off;

  float*          wg   = (float*)(ws + o_w);
  int*            wi   = (int*)  (ws + o_wi);
  unsigned short* Bh   = (unsigned short*)(ws + o_bh);
  unsigned short* Uh   = (unsigned short*)(ws + o_uh);
  unsigned short* Ul   = (unsigned short*)(ws + o_ul);
  float*          bsq  = (float*)(ws + o_bsq);
  float*          shr  = (float*)(ws + o_shr);
  float*          mkT  = (float*)(ws + o_mkT);
  float*          pmx  = (float*)(ws + o_pm);

  const size_t mvh_sz = (size_t)NMEM * 1024 * 2;   // 58.7 MB fp16

  k_prep_b<<<NMEM / 256, 256, 0, stream>>>(mem_key, mem_shr, Bh, mkT, shr);
  k_prep_u<<<HW / 256, 256, 0, stream>>>(q_key, q_sel, Uh, Ul, bsq);
  k_sim<<<SIMB, 256, 0, stream>>>(Uh, Ul, Bh, bsq, shr, pmx);
  k_select<<<HW / 4, 256, 0, stream>>>(pmx, mkT, q_key, q_sel, shr, wg, wi);

  if (ws_size >= o_end + mvh_sz) {
    _Float16* mvT = (_Float16*)(ws + o_end);
    k_transpose_h<<<dim3(NMEM / 64, 16), 256, 0, stream>>>(mem_value, mvT);
    k_gather_h<<<dim3(HW / 8, 4), 256, 0, stream>>>(mvT, wg, wi, out);
  } else if (ws_size >= o_pr + mvh_sz) {
    _Float16* mvT = (_Float16*)(ws + o_pr);        // Bh..pmx dead after select
    k_transpose_h<<<dim3(NMEM / 64, 16), 256, 0, stream>>>(mem_value, mvT);
    k_gather_h<<<dim3(HW / 8, 4), 256, 0, stream>>>(mvT, wg, wi, out);
  } else {
    k_gather_f<<<dim3(HW / 8, 4), 256, 0, stream>>>(
        mem_value, wg, wi, out, 1, NMEM);
  }
}

// Round 12
// 155.775 us; speedup vs baseline: 1.2816x; 1.0893x over previous
//
#include <hip/hip_runtime.h>
#include <math.h>

#define HW      1792
#define NMEM    28672
#define NCHUNK  3584          // NMEM/8 chunks of 8
#define TOPK    30
#define CTARGET 48
#define SCAP    64            // survivor chunk cap -> NC <= 512
#define FINCAP  64
#define SIMB    448           // 14 p-blocks(128px) x 32 strips
#define WPS     7             // 128-n windows per strip
#define NSELB   448           // select blocks (4 pixels each)

typedef __attribute__((ext_vector_type(8))) short bf16x8;
typedef __attribute__((ext_vector_type(8))) unsigned short u16x8;
typedef __attribute__((ext_vector_type(4))) float f32x4;
typedef __attribute__((ext_vector_type(4))) _Float16 h4;
typedef unsigned long long ull;

static __device__ __forceinline__ unsigned short f2bf(float v) {
  unsigned b = __float_as_uint(v);
  return (unsigned short)((b + 0x7FFFu + ((b >> 16) & 1u)) >> 16);
}
static __device__ __forceinline__ float bf2f(unsigned short h) {
  return __uint_as_float(((unsigned)h) << 16);
}
static __device__ __forceinline__ unsigned fkey(float v) {
  return __float_as_uint(-v) & 0x7FFFFFFFu;
}
static __device__ __forceinline__ void gl_lds16(const void* g, void* l) {
  __builtin_amdgcn_global_load_lds(
      (const __attribute__((address_space(1))) unsigned*)g,
      (__attribute__((address_space(3))) unsigned*)l, 16, 0, 0);
}
// wave-scope LDS handoff: drain ds ops + block compiler reordering
#define WSYNC() do { asm volatile("s_waitcnt lgkmcnt(0)" ::: "memory"); \
                     __builtin_amdgcn_wave_barrier(); } while (0)

// ---------------------------------------------------------------------------
// Prep B: Bh[s][n][8] bf16-hi (s=0..7: mk, s=8..15: mk^2); mkT[n][64] fp32;
// shr_s = mem_shr/8.
// ---------------------------------------------------------------------------
__global__ __launch_bounds__(256)
void k_prep_b(const float* __restrict__ mk, const float* __restrict__ shr_in,
              unsigned short* __restrict__ Bh,
              float* __restrict__ mkT, float* __restrict__ shr_s)
{
  const int n = blockIdx.x * 256 + threadIdx.x;
  shr_s[n] = shr_in[n] * 0.125f;
  for (int cb = 0; cb < 64; cb += 8) {
    u16x8 h1, h2;
    float vv[8];
    #pragma unroll
    for (int j = 0; j < 8; ++j) {
      float v = mk[(size_t)(cb + j) * NMEM + n];
      vv[j] = v;
      h1[j] = f2bf(v);
      h2[j] = f2bf(v * v);
    }
    const int s = cb >> 3;
    *reinterpret_cast<u16x8*>(&Bh[((size_t)s * NMEM + n) * 8])       = h1;
    *reinterpret_cast<u16x8*>(&Bh[((size_t)(s + 8) * NMEM + n) * 8]) = h2;
    *reinterpret_cast<float4*>(&mkT[(size_t)n * 64 + cb])     = make_float4(vv[0], vv[1], vv[2], vv[3]);
    *reinterpret_cast<float4*>(&mkT[(size_t)n * 64 + cb + 4]) = make_float4(vv[4], vv[5], vv[6], vv[7]);
  }
}

// ---------------------------------------------------------------------------
// Prep U: Uh/Ul[s][p][8] bf16 hi/lo. s=0..7: 2*qk*qs, s=8..15: -qs. bsq[p].
// ---------------------------------------------------------------------------
__global__ __launch_bounds__(256)
void k_prep_u(const float* __restrict__ q_key, const float* __restrict__ q_sel,
              unsigned short* __restrict__ Uh, unsigned short* __restrict__ Ul,
              float* __restrict__ bsq)
{
  const int p = blockIdx.x * 256 + threadIdx.x;
  float bs = 0.f;
  for (int cb = 0; cb < 64; cb += 8) {
    u16x8 h1, l1, h2, l2;
    #pragma unroll
    for (int j = 0; j < 8; ++j) {
      int c = cb + j;
      float k = q_key[(size_t)c * HW + p];
      float s = q_sel[(size_t)c * HW + p];
      float u = 2.f * k * s;
      float w = -s;
      bs = fmaf(s * k, k, bs);
      unsigned short h = f2bf(u); h1[j] = h; l1[j] = f2bf(u - bf2f(h));
      unsigned short g = f2bf(w); h2[j] = g; l2[j] = f2bf(w - bf2f(g));
    }
    const int s = cb >> 3;
    *reinterpret_cast<u16x8*>(&Uh[((size_t)s * HW + p) * 8])       = h1;
    *reinterpret_cast<u16x8*>(&Ul[((size_t)s * HW + p) * 8])       = l1;
    *reinterpret_cast<u16x8*>(&Uh[((size_t)(s + 8) * HW + p) * 8]) = h2;
    *reinterpret_cast<u16x8*>(&Ul[((size_t)(s + 8) * HW + p) * 8]) = l2;
  }
  bsq[p] = bs;
}

// ---------------------------------------------------------------------------
// Sim kernel: 128 pixels x 7-window strip per block (448 blocks). Unchanged.
// ---------------------------------------------------------------------------
__global__ __launch_bounds__(256, 2)
void k_sim(const unsigned short* __restrict__ Uh, const unsigned short* __restrict__ Ul,
           const unsigned short* __restrict__ Bh,
           const float* __restrict__ bsq, const float* __restrict__ shr_s,
           float* __restrict__ pmax)
{
  __shared__ char smem[65536] __attribute__((aligned(16)));
  const int tid = threadIdx.x;
  const int wid = tid >> 6, lane = tid & 63;
  const int lr = lane & 15, lg = lane >> 4;
  const int pb = blockIdx.x % 14, st = blockIdx.x / 14;
  const int pw = pb * 128 + wid * 32;
  const int w0 = st * WPS;

  bf16x8 a0h[4], a0l[4], a1h[4], a1l[4];
  #pragma unroll
  for (int t = 0; t < 4; ++t) {
    const size_t e0 = ((size_t)(t * 4 + lg) * HW + pw + lr) * 8;
    const size_t e1 = e0 + 16 * 8;
    a0h[t] = *reinterpret_cast<const bf16x8*>(&Uh[e0]);
    a0l[t] = *reinterpret_cast<const bf16x8*>(&Ul[e0]);
    a1h[t] = *reinterpret_cast<const bf16x8*>(&Uh[e1]);
    a1l[t] = *reinterpret_cast<const bf16x8*>(&Ul[e1]);
  }
  float bq[2][4];
  #pragma unroll
  for (int pt = 0; pt < 2; ++pt)
    #pragma unroll
    for (int r = 0; r < 4; ++r) bq[pt][r] = bsq[pw + pt * 16 + 4 * lg + r];

  auto stage = [&](int buf, int i) {
    const int n0 = (w0 + i) * 128;
    #pragma unroll
    for (int j = 0; j < 8; ++j) {
      const int idx = j * 256 + tid;
      const int s = idx >> 7, rr = idx & 127;
      gl_lds16((const char*)Bh + ((size_t)s * NMEM + n0 + rr) * 16,
               smem + buf * 32768 + idx * 16);
    }
  };

  stage(0, 0);
  int buf = 0;
  for (int i = 0; i < WPS; ++i) {
    __syncthreads();
    if (i + 1 < WPS) stage(buf ^ 1, i + 1);

    f32x4 acc[2][8];
    #pragma unroll
    for (int a = 0; a < 2; ++a)
      #pragma unroll
      for (int b = 0; b < 8; ++b) acc[a][b] = (f32x4){0.f, 0.f, 0.f, 0.f};

    const short* lb = (const short*)(smem + buf * 32768);
    #pragma unroll
    for (int t = 0; t < 4; ++t) {
      #pragma unroll
      for (int nt = 0; nt < 8; ++nt) {
        bf16x8 bh = *reinterpret_cast<const bf16x8*>(
            &lb[((t * 4 + lg) * 128 + nt * 16 + lr) * 8]);
        acc[0][nt] = __builtin_amdgcn_mfma_f32_16x16x32_bf16(a0h[t], bh, acc[0][nt], 0, 0, 0);
        acc[0][nt] = __builtin_amdgcn_mfma_f32_16x16x32_bf16(a0l[t], bh, acc[0][nt], 0, 0, 0);
        acc[1][nt] = __builtin_amdgcn_mfma_f32_16x16x32_bf16(a1h[t], bh, acc[1][nt], 0, 0, 0);
        acc[1][nt] = __builtin_amdgcn_mfma_f32_16x16x32_bf16(a1l[t], bh, acc[1][nt], 0, 0, 0);
      }
    }

    const int wgl = w0 + i;
    const int n0 = wgl * 128;
    float shv[8];
    #pragma unroll
    for (int nt = 0; nt < 8; ++nt) shv[nt] = shr_s[n0 + nt * 16 + lr];
    #pragma unroll
    for (int pt = 0; pt < 2; ++pt) {
      #pragma unroll
      for (int r = 0; r < 4; ++r) {
        float mx = -INFINITY;
        #pragma unroll
        for (int nt = 0; nt < 8; ++nt)
          mx = fmaxf(mx, (acc[pt][nt][r] - bq[pt][r]) * shv[nt]);
        pmax[(size_t)(pw + pt * 16 + 4 * lg + r) * NCHUNK + wgl * 16 + lr] = mx;
      }
    }
    buf ^= 1;
  }
}

// ---------------------------------------------------------------------------
// Shared memory: select state (28.5 KB) unioned with transpose tile
// ---------------------------------------------------------------------------
struct SelS {
  int   hist[4][512];     // 8 KB, phys-transposed bins
  ull   pk[4][512];       // 16 KB packed (val,idx) keys
  ull   fin[4][FINCAP];   // 2 KB finalists
  short sl[4][SCAP];      // survivor chunk ids
  float sqk[4][64], sqs[4][64];
};
union SMemU { SelS sel; float tt[64][65]; };

// phys index for logical bin b (512 bins, 8 owned per lane): conflict-free scan
static __device__ __forceinline__ int ph(int b) { return ((b & 7) << 6) | (b >> 3); }

// wave crossing over 512-bin hist: smallest B with prefix(<B) < target <= prefix(<=B)
static __device__ __forceinline__ void wave_cross8(const int* h, int lane, int target,
                                                   int& B, int& nA)
{
  int hv[8]; int ls = 0;
  #pragma unroll
  for (int k = 0; k < 8; ++k) { hv[k] = h[(k << 6) + lane]; ls += hv[k]; }
  int sc = ls;
  #pragma unroll
  for (int off = 1; off < 64; off <<= 1) {
    int t = __shfl_up(sc, off);
    if (lane >= off) sc += t;
  }
  int run = sc - ls;
  int myB = -1, mynA = 0;
  #pragma unroll
  for (int k = 0; k < 8; ++k) {
    if (run < target && run + hv[k] >= target) { myB = lane * 8 + k; mynA = run; }
    run += hv[k];
  }
  ull ball = __ballot(myB >= 0);
  int src = __ffsll((long long)ball) - 1;
  B = __shfl(myB, src); nA = __shfl(mynA, src);
}

// ---------------------------------------------------------------------------
// Fused select(+transpose) kernel. Select: one pixel per wave, zero block
// barriers, rank-based final selection (no serial argmax rounds).
// Transpose blocks (16 per select block) hide inside select's latency shadow.
// ---------------------------------------------------------------------------
__global__ __launch_bounds__(256, 4)
void k_selT(const float* __restrict__ pmax, const float* __restrict__ mkT,
            const float* __restrict__ q_key, const float* __restrict__ q_sel,
            const float* __restrict__ shr_s,
            float* __restrict__ wgt, int* __restrict__ widx,
            const float* __restrict__ mv, _Float16* __restrict__ mvT)
{
  __shared__ SMemU sm;
  const int tid = threadIdx.x;

  int sg = -1, tb = -1;
  if (gridDim.x > NSELB) {
    const int g = blockIdx.x / 17, r = blockIdx.x % 17;
    if (r == 0) sg = g; else tb = g * 16 + (r - 1);
  } else {
    sg = blockIdx.x;
  }

  if (tb >= 0) {
    // ---- transpose block: 64n x 64ch fp32 -> fp16
    const int n0 = (tb % 448) * 64, ch0 = (tb / 448) * 64;
    for (int i = tid; i < 64 * 16; i += 256) {
      int r = i >> 4, c4 = (i & 15) << 2;
      float4 v = *reinterpret_cast<const float4*>(&mv[(size_t)(ch0 + r) * NMEM + n0 + c4]);
      sm.tt[r][c4] = v.x; sm.tt[r][c4 + 1] = v.y;
      sm.tt[r][c4 + 2] = v.z; sm.tt[r][c4 + 3] = v.w;
    }
    __syncthreads();
    for (int i = tid; i < 64 * 16; i += 256) {
      int r = i >> 4, c4 = (i & 15) << 2;
      h4 hv = {(_Float16)sm.tt[c4][r], (_Float16)sm.tt[c4 + 1][r],
               (_Float16)sm.tt[c4 + 2][r], (_Float16)sm.tt[c4 + 3][r]};
      *reinterpret_cast<h4*>(&mvT[(size_t)(n0 + r) * 1024 + ch0 + c4]) = hv;
    }
    return;
  }

  const int w = tid >> 6, lane = tid & 63;
  const int pix = sg * 4 + w;
  int*   h  = sm.sel.hist[w];
  ull*   p  = sm.sel.pk[w];
  ull*   fin = sm.sel.fin[w];
  short* sl = sm.sel.sl[w];

  sm.sel.sqk[w][lane] = q_key[(size_t)lane * HW + pix];
  sm.sel.sqs[w][lane] = q_sel[(size_t)lane * HW + pix];

  // ---- load chunk maxima (56/lane, coalesced)
  float m[56];
  const float* pm = pmax + (size_t)pix * NCHUNK;
  #pragma unroll
  for (int j = 0; j < 56; ++j) m[j] = pm[lane + 64 * j];

  // ---- stage 1 L1: 9-bit histogram (fkey >> 22)
  #pragma unroll
  for (int k = 0; k < 8; ++k) h[lane + 64 * k] = 0;
  WSYNC();
  #pragma unroll
  for (int j = 0; j < 56; ++j) atomicAdd(&h[ph(fkey(m[j]) >> 22)], 1);
  WSYNC();
  int B1, nA1;
  wave_cross8(h, lane, CTARGET, B1, nA1);

  // ---- stage 1 L2: refine boundary over key bits 21..13
  #pragma unroll
  for (int k = 0; k < 8; ++k) h[lane + 64 * k] = 0;
  WSYNC();
  #pragma unroll
  for (int j = 0; j < 56; ++j) {
    unsigned u = fkey(m[j]);
    if ((int)(u >> 22) == B1) atomicAdd(&h[ph((u >> 13) & 511)], 1);
  }
  WSYNC();
  int Bs1, nAs1;
  wave_cross8(h, lane, CTARGET - nA1, Bs1, nAs1);

  // ---- survivors (ballot-compacted, deterministic chunk order)
  int nsurv = 0;
  #pragma unroll
  for (int j = 0; j < 56; ++j) {
    unsigned u = fkey(m[j]);
    int b1 = (int)(u >> 22);
    bool keep = (b1 < B1) || (b1 == B1 && (int)((u >> 13) & 511) <= Bs1);
    ull ball = __ballot(keep);
    if (keep) {
      int pos = nsurv + __popcll(ball & ((1ull << lane) - 1ull));
      if (pos < SCAP) sl[pos] = (short)(lane + 64 * j);
    }
    nsurv += __popcll(ball);
  }
  nsurv = (nsurv < SCAP) ? nsurv : SCAP;
  const int NC = nsurv * 8;
  WSYNC();

  // ---- stage 2: exact fp32 sims -> packed keys (larger = better)
  const float4* k4p = reinterpret_cast<const float4*>(sm.sel.sqk[w]);
  const float4* s4p = reinterpret_cast<const float4*>(sm.sel.sqs[w]);
  for (int c = lane; c < NC; c += 64) {
    const int cc = sl[c >> 3];
    const int n = ((cc >> 4) << 7) + (cc & 15) + ((c & 7) << 4);
    const float4* mr = reinterpret_cast<const float4*>(mkT + (size_t)n * 64);
    float s0 = 0.f, s1 = 0.f, s2 = 0.f, s3 = 0.f;
    #pragma unroll
    for (int j = 0; j < 4; ++j) {
      float4 q0 = mr[4 * j], q1 = mr[4 * j + 1], q2 = mr[4 * j + 2], q3 = mr[4 * j + 3];
      float4 a0 = k4p[4 * j], a1 = k4p[4 * j + 1], a2 = k4p[4 * j + 2], a3 = k4p[4 * j + 3];
      float4 b0 = s4p[4 * j], b1 = s4p[4 * j + 1], b2 = s4p[4 * j + 2], b3 = s4p[4 * j + 3];
      float d;
      d = q0.x - a0.x; s0 = fmaf(b0.x * d, d, s0);
      d = q0.y - a0.y; s1 = fmaf(b0.y * d, d, s1);
      d = q0.z - a0.z; s2 = fmaf(b0.z * d, d, s2);
      d = q0.w - a0.w; s3 = fmaf(b0.w * d, d, s3);
      d = q1.x - a1.x; s0 = fmaf(b1.x * d, d, s0);
      d = q1.y - a1.y; s1 = fmaf(b1.y * d, d, s1);
      d = q1.z - a1.z; s2 = fmaf(b1.z * d, d, s2);
      d = q1.w - a1.w; s3 = fmaf(b1.w * d, d, s3);
      d = q2.x - a2.x; s0 = fmaf(b2.x * d, d, s0);
      d = q2.y - a2.y; s1 = fmaf(b2.y * d, d, s1);
      d = q2.z - a2.z; s2 = fmaf(b2.z * d, d, s2);
      d = q2.w - a2.w; s3 = fmaf(b2.w * d, d, s3);
      d = q3.x - a3.x; s0 = fmaf(b3.x * d, d, s0);
      d = q3.y - a3.y; s1 = fmaf(b3.y * d, d, s1);
      d = q3.z - a3.z; s2 = fmaf(b3.z * d, d, s2);
      d = q3.w - a3.w; s3 = fmaf(b3.w * d, d, s3);
    }
    float v = -((s0 + s1) + (s2 + s3)) * shr_s[n];
    p[c] = ((ull)(0x7FFFFFFFu - fkey(v)) << 32) |
           (ull)(0xFFFFFFFFu - (unsigned)n);
  }
  WSYNC();

  // ---- finale L1: histogram of candidate keys (9 bits)
  #pragma unroll
  for (int k = 0; k < 8; ++k) h[lane + 64 * k] = 0;
  WSYNC();
  for (int c = lane; c < NC; c += 64) {
    unsigned qk = 0x7FFFFFFFu - (unsigned)(p[c] >> 32);
    atomicAdd(&h[ph(qk >> 22)], 1);
  }
  WSYNC();
  int B2, nA2;
  wave_cross8(h, lane, TOPK, B2, nA2);

  // ---- finale L2
  #pragma unroll
  for (int k = 0; k < 8; ++k) h[lane + 64 * k] = 0;
  WSYNC();
  for (int c = lane; c < NC; c += 64) {
    unsigned qk = 0x7FFFFFFFu - (unsigned)(p[c] >> 32);
    if ((int)(qk >> 22) == B2) atomicAdd(&h[ph((qk >> 13) & 511)], 1);
  }
  WSYNC();
  int Bs2, nAs2;
  wave_cross8(h, lane, TOPK - nA2, Bs2, nAs2);

  // ---- collect finalists (<= 64, deterministic ballot order)
  int nfin = 0;
  for (int c0 = 0; c0 < NC; c0 += 64) {
    int c = c0 + lane;
    bool isf = false; ull key = 0ull;
    if (c < NC) {
      key = p[c];
      unsigned qk = 0x7FFFFFFFu - (unsigned)(key >> 32);
      int b1 = (int)(qk >> 22);
      isf = (b1 < B2) || (b1 == B2 && (int)((qk >> 13) & 511) <= Bs2);
    }
    ull ball = __ballot(isf);
    if (isf) {
      int pos = nfin + __popcll(ball & ((1ull << lane) - 1ull));
      if (pos < FINCAP) fin[pos] = key;
    }
    nfin += __popcll(ball);
  }
  WSYNC();
  const int nf = (nfin < FINCAP) ? nfin : FINCAP;

  // ---- pairwise ballot-rank (exact, (value, lower-idx) order)
  ull myk = (lane < nf) ? fin[lane] : 0ull;
  int r = 0;
  #pragma unroll
  for (int sft = 1; sft < 64; ++sft) {
    ull ok = __shfl_xor(myk, sft);
    r += (ok > myk) ? 1 : 0;
  }
  float v = -__uint_as_float(0x7FFFFFFFu - (unsigned)(myk >> 32));
  bool sel = (lane < nf) && (r < TOPK);
  float e = sel ? expf(v) : 0.f;
  float es = e;
  #pragma unroll
  for (int off = 32; off > 0; off >>= 1) es += __shfl_xor(es, off);
  if (sel) {
    wgt [(size_t)pix * 32 + r] = e / es;
    widx[(size_t)pix * 32 + r] = (int)(0xFFFFFFFFu - (unsigned)(myk & 0xFFFFFFFFu));
  }
}

// ---------------------------------------------------------------------------
// Standalone fp16 transpose (fallback, overlay mode)
// ---------------------------------------------------------------------------
__global__ __launch_bounds__(256)
void k_transpose_h(const float* __restrict__ mv, _Float16* __restrict__ mvT)
{
  __shared__ float t[64][65];
  const int n0 = blockIdx.x * 64, ch0 = blockIdx.y * 64;
  const int tid = threadIdx.x;
  for (int i = tid; i < 64 * 16; i += 256) {
    int r = i >> 4, c4 = (i & 15) << 2;
    float4 v = *reinterpret_cast<const float4*>(&mv[(size_t)(ch0 + r) * NMEM + n0 + c4]);
    t[r][c4] = v.x; t[r][c4 + 1] = v.y; t[r][c4 + 2] = v.z; t[r][c4 + 3] = v.w;
  }
  __syncthreads();
  for (int i = tid; i < 64 * 16; i += 256) {
    int r = i >> 4, c4 = (i & 15) << 2;
    h4 hv = {(_Float16)t[c4][r], (_Float16)t[c4 + 1][r],
             (_Float16)t[c4 + 2][r], (_Float16)t[c4 + 3][r]};
    *reinterpret_cast<h4*>(&mvT[(size_t)(n0 + r) * 1024 + ch0 + c4]) = hv;
  }
}

// ---------------------------------------------------------------------------
// Gather (fp16 source): out[ch][p] = sum_k w[p][k] * mvT[idx[p][k]][ch]
// ---------------------------------------------------------------------------
__global__ __launch_bounds__(256)
void k_gather_h(const _Float16* __restrict__ mvT, const float* __restrict__ wgt,
                const int* __restrict__ widx, float* __restrict__ out)
{
  __shared__ float sw[8][TOPK];
  __shared__ int   si[8][TOPK];
  __shared__ float sbuf[256][9];
  const int p0 = blockIdx.x * 8, chg = blockIdx.y * 256;
  const int tid = threadIdx.x;

  for (int i = tid; i < 8 * TOPK; i += 256) {
    int q = i / TOPK, k = i - q * TOPK;
    sw[q][k] = wgt [(size_t)(p0 + q) * 32 + k];
    si[q][k] = widx[(size_t)(p0 + q) * 32 + k];
  }
  __syncthreads();

  const int ch = chg + tid;
  #pragma unroll 2
  for (int q = 0; q < 8; ++q) {
    float a = 0.f;
    #pragma unroll
    for (int k = 0; k < TOPK; ++k)
      a = fmaf(sw[q][k], (float)mvT[(size_t)si[q][k] * 1024 + ch], a);
    sbuf[tid][q] = a;
  }
  __syncthreads();

  for (int i = tid; i < 256 * 8; i += 256) {
    int cl = i >> 3, q = i & 7;
    out[(size_t)(chg + cl) * HW + p0 + q] = sbuf[cl][q];
  }
}

// ---------------------------------------------------------------------------
// Gather (fp32 strided source, raw fallback)
// ---------------------------------------------------------------------------
__global__ __launch_bounds__(256)
void k_gather_f(const float* __restrict__ src, const float* __restrict__ wgt,
                const int* __restrict__ widx, float* __restrict__ out,
                long n_stride, long ch_stride)
{
  __shared__ float sw[8][TOPK];
  __shared__ int   si[8][TOPK];
  __shared__ float sbuf[256][9];
  const int p0 = blockIdx.x * 8, chg = blockIdx.y * 256;
  const int tid = threadIdx.x;

  for (int i = tid; i < 8 * TOPK; i += 256) {
    int q = i / TOPK, k = i - q * TOPK;
    sw[q][k] = wgt [(size_t)(p0 + q) * 32 + k];
    si[q][k] = widx[(size_t)(p0 + q) * 32 + k];
  }
  __syncthreads();

  const int ch = chg + tid;
  #pragma unroll 2
  for (int q = 0; q < 8; ++q) {
    float a = 0.f;
    #pragma unroll
    for (int k = 0; k < TOPK; ++k)
      a = fmaf(sw[q][k], src[(size_t)si[q][k] * n_stride + (size_t)ch * ch_stride], a);
    sbuf[tid][q] = a;
  }
  __syncthreads();

  for (int i = tid; i < 256 * 8; i += 256) {
    int cl = i >> 3, q = i & 7;
    out[(size_t)(chg + cl) * HW + p0 + q] = sbuf[cl][q];
  }
}

// ---------------------------------------------------------------------------
extern "C" void kernel_launch(void* const* d_in, const int* in_sizes, int n_in,
                              void* d_out, int out_size, void* d_ws, size_t ws_size,
                              hipStream_t stream)
{
  (void)in_sizes; (void)n_in; (void)out_size;
  const float* q_key     = (const float*)d_in[0];
  const float* q_sel     = (const float*)d_in[1];
  const float* mem_key   = (const float*)d_in[2];
  const float* mem_shr   = (const float*)d_in[3];
  const float* mem_value = (const float*)d_in[4];
  float* out = (float*)d_out;

  char* ws = (char*)d_ws;
  size_t off = 0;
  auto alloc = [&](size_t b) { size_t c = off; off = (off + b + 255) & ~(size_t)255; return c; };
  size_t o_w   = alloc((size_t)HW * 32 * 4);
  size_t o_wi  = alloc((size_t)HW * 32 * 4);
  size_t o_pr  = off;                              // overlay point (fallback)
  size_t o_bh  = alloc((size_t)NMEM * 128 * 2);    // 7.34 MB
  size_t o_uh  = alloc((size_t)HW * 128 * 2);
  size_t o_ul  = alloc((size_t)HW * 128 * 2);
  size_t o_bsq = alloc((size_t)HW * 4);
  size_t o_shr = alloc((size_t)NMEM * 4);
  size_t o_mkT = alloc((size_t)NMEM * 64 * 4);     // 7.34 MB
  size_t o_pm  = alloc((size_t)HW * NCHUNK * 4);   // 25.7 MB
  size_t o_end = off;

  float*          wg   = (float*)(ws + o_w);
  int*            wi   = (int*)  (ws + o_wi);
  unsigned short* Bh   = (unsigned short*)(ws + o_bh);
  unsigned short* Uh   = (unsigned short*)(ws + o_uh);
  unsigned short* Ul   = (unsigned short*)(ws + o_ul);
  float*          bsq  = (float*)(ws + o_bsq);
  float*          shr  = (float*)(ws + o_shr);
  float*          mkT  = (float*)(ws + o_mkT);
  float*          pmx  = (float*)(ws + o_pm);

  const size_t mvh_sz = (size_t)NMEM * 1024 * 2;   // 58.7 MB fp16

  k_prep_b<<<NMEM / 256, 256, 0, stream>>>(mem_key, mem_shr, Bh, mkT, shr);
  k_prep_u<<<HW / 256, 256, 0, stream>>>(q_key, q_sel, Uh, Ul, bsq);
  k_sim<<<SIMB, 256, 0, stream>>>(Uh, Ul, Bh, bsq, shr, pmx);

  if (ws_size >= o_end + mvh_sz) {
    // fused: select (448 blocks, 4px each) + transpose (7168), 1:16
    _Float16* mvT = (_Float16*)(ws + o_end);
    k_selT<<<NSELB * 17, 256, 0, stream>>>(pmx, mkT, q_key, q_sel, shr,
                                           wg, wi, mem_value, mvT);
    k_gather_h<<<dim3(HW / 8, 4), 256, 0, stream>>>(mvT, wg, wi, out);
  } else if (ws_size >= o_pr + mvh_sz) {
    // fallback: select only, then transpose into overlay region
    k_selT<<<NSELB, 256, 0, stream>>>(pmx, mkT, q_key, q_sel, shr,
                                      wg, wi, mem_value, nullptr);
    _Float16* mvT = (_Float16*)(ws + o_pr);        // Bh..pmx dead after select
    k_transpose_h<<<dim3(NMEM / 64, 16), 256, 0, stream>>>(mem_value, mvT);
    k_gather_h<<<dim3(HW / 8, 4), 256, 0, stream>>>(mvT, wg, wi, out);
  } else {
    k_selT<<<NSELB, 256, 0, stream>>>(pmx, mkT, q_key, q_sel, shr,
                                      wg, wi, mem_value, nullptr);
    k_gather_f<<<dim3(HW / 8, 4), 256, 0, stream>>>(
        mem_value, wg, wi, out, 1, NMEM);
  }
}